// Round 2
// baseline (1111.588 us; speedup 1.0000x reference)
//
#include <hip/hip_runtime.h>
#include <math.h>
#include <limits.h>

#define NNODE 10000
#define INCH  9998
#define NEDGE 320000
#define KC    128
#define KPAD  10240
#define NCHH  40          // chunks per K-half (total 80 chunks * 128 = 10240)

__device__ __forceinline__ float lrelu(float v){ return v > 0.f ? v : 0.2f*v; }
__device__ __forceinline__ float frelu(float v){ return v > 0.f ? v : 0.f; }
__device__ __forceinline__ int   fkey(float f){ int i = __float_as_int(f); return i >= 0 ? i : (i ^ 0x7FFFFFFF); }
__device__ __forceinline__ float fdec(int k){ return __int_as_float(k >= 0 ? k : (k ^ 0x7FFFFFFF)); }

#define GLOAD_LDS16(g, l) __builtin_amdgcn_global_load_lds( \
    (const __attribute__((address_space(1))) unsigned int*)(g), \
    (__attribute__((address_space(3))) unsigned int*)(l), 16, 0, 0)

// ---------------------------------------------------------------------------
// Pre-transpose weights: WT[c][k] = Wcat[k][c], zero-padded to KPAD.
// c: 0..7 = Wl1 cols, 8..15 = Wr1 cols, 16..79 = enc_W1 cols.
__global__ void prep_wt(const float* __restrict__ Wl, const float* __restrict__ Wr,
                        const float* __restrict__ We, float* __restrict__ WT){
  int idx = blockIdx.x*256 + threadIdx.x;
  if (idx >= 80*KPAD) return;
  int c = idx / KPAD;
  int k = idx - c*KPAD;
  float v = 0.f;
  if (k < INCH)
    v = (c < 8) ? Wl[k*8 + c] : (c < 16 ? Wr[k*8 + (c-8)] : We[k*64 + (c-16)]);
  WT[idx] = v;
}

// ---------------------------------------------------------------------------
// Fused 80-column GEMM over x: cols 0..7 -> xl1(+bl1), 8..15 -> xr1(+br1),
// 16..79 -> encp. Grid: 1252 = 626 row-slices (16 rows each) x 2 K-halves.
// Block: 512 thr = 8 waves = 2 rowgroups(8 rows/lane) x 4 colgroups(20 cols).
// W chunk (80x128 = 40KB) double-buffered in LDS via global_load_lds;
// x double-buffered in registers (float2/lane, rows are 8B-aligned).
__global__ __launch_bounds__(512, 2)
void k1_fused(const float* __restrict__ x, const float* __restrict__ WT,
              const float* __restrict__ bl1, const float* __restrict__ br1,
              float* __restrict__ xl1, float* __restrict__ xr1,
              float* __restrict__ encp){
  __shared__ float lds[2][80*KC];
  const int tid  = threadIdx.x;
  const int lane = tid & 63;
  const int w    = tid >> 6;     // 0..7
  const int cg   = w & 3;        // colgroup: cols cg*20..cg*20+19
  const int g    = w >> 2;       // rowgroup 0/1
  const int sid  = blockIdx.x;
  const int kh   = sid & 1;      // K half
  const int rs   = sid >> 1;     // row slice 0..625 (rows rs*16..rs*16+15)
  const int ch0  = kh*NCHH;
  const int maxi = NNODE*INCH - 2;

  // stage W chunk ch0 into buffer 0 (async; lane i writes seg_base + 16B*i)
  {
    const int k0 = ch0*KC;
    #pragma unroll
    for (int i = 0; i < 5; ++i) {
      int seg = w*5 + i;   // 40 segments of 1KB (2 W rows each)
      const float* gp = WT + (size_t)(2*seg + (lane>>5))*KPAD + k0 + ((lane&31)<<2);
      GLOAD_LDS16(gp, &lds[0][0] + seg*256);
    }
  }

  float acc[8][20];
  #pragma unroll
  for (int r = 0; r < 8; ++r)
    #pragma unroll
    for (int c = 0; c < 20; ++c) acc[r][c] = 0.f;

  // prefetch x for first chunk
  float2 xn[8];
  #pragma unroll
  for (int r = 0; r < 8; ++r) {
    int rw = rs*16 + g*8 + r;
    int xi = rw*INCH + ch0*KC + (lane<<1);
    xi = min(xi, maxi);
    xn[r] = *(const float2*)(x + xi);
  }

  for (int ci = 0; ci < NCHH; ++ci) {
    const int cur = ci & 1;
    __syncthreads();   // drains vmcnt(0): buf[cur] staged, prefetched x landed,
                       // and all waves are done reading buf[cur^1]
    if (ci + 1 < NCHH) {            // async-stage next chunk into other buffer
      const int k0n = (ch0 + ci + 1)*KC;
      #pragma unroll
      for (int i = 0; i < 5; ++i) {
        int seg = w*5 + i;
        const float* gp = WT + (size_t)(2*seg + (lane>>5))*KPAD + k0n + ((lane&31)<<2);
        GLOAD_LDS16(gp, &lds[cur^1][0] + seg*256);
      }
    }

    float2 xv[8];
    #pragma unroll
    for (int r = 0; r < 8; ++r) xv[r] = xn[r];
    if (ci + 1 < NCHH) {            // prefetch next chunk's x into regs
      const int k0n = (ch0 + ci + 1)*KC;
      #pragma unroll
      for (int r = 0; r < 8; ++r) {
        int rw = rs*16 + g*8 + r;
        int xi = rw*INCH + k0n + (lane<<1);
        xi = min(xi, maxi);
        xn[r] = *(const float2*)(x + xi);
      }
    }

    const float* wl = &lds[cur][0] + cg*20*KC + (lane<<1);
    #pragma unroll
    for (int cs = 0; cs < 20; ++cs) {
      float2 wv = *(const float2*)(wl + cs*KC);
      #pragma unroll
      for (int r = 0; r < 8; ++r) {
        acc[r][cs] = fmaf(xv[r].x, wv.x, acc[r][cs]);
        acc[r][cs] = fmaf(xv[r].y, wv.y, acc[r][cs]);
      }
    }
  }

  // cross-lane reduce (64-lane butterfly; every lane ends with all 160 sums)
  #pragma unroll
  for (int m = 1; m < 64; m <<= 1)
    #pragma unroll
    for (int r = 0; r < 8; ++r)
      #pragma unroll
      for (int cs = 0; cs < 20; ++cs)
        acc[r][cs] += __shfl_xor(acc[r][cs], m, 64);

  float vout[3];
  vout[0] = 0.f; vout[1] = 0.f; vout[2] = 0.f;
  #pragma unroll
  for (int o = 0; o < 160; ++o)
    if ((o & 63) == lane) vout[o >> 6] = acc[o/20][o%20];   // static indices

  #pragma unroll
  for (int t = 0; t < 3; ++t) {
    int o = lane + (t << 6);
    if (o < 160) {
      int r  = o / 20;
      int cs = o - r*20;
      int rw = rs*16 + g*8 + r;
      if (rw < NNODE) {
        int col = cg*20 + cs;
        float val = vout[t];
        if (kh == 0) {
          if (col < 8)       val += bl1[col];
          else if (col < 16) val += br1[col - 8];
        }
        if (col < 8)       atomicAdd(xl1 + rw*8 + col, val);
        else if (col < 16) atomicAdd(xr1 + rw*8 + col - 8, val);
        else               atomicAdd(encp + rw*64 + col - 16, val);
      }
    }
  }
}

// ---------------------------------------------------------------------------
// Per-conv init: mkey = INT_MIN (memset 0x80 is NOT a lower bound for fkey!),
// denom = 0, gat = 0.
__global__ void init_conv(int* __restrict__ mkey, float* __restrict__ denom,
                          float* __restrict__ gat){
  int i = blockIdx.x*256 + threadIdx.x;
  if (i < NNODE*2) { mkey[i] = INT_MIN; denom[i] = 0.f; }
  if (i < NNODE*8) gat[i] = 0.f;
}

// ---------------------------------------------------------------------------
// Edge passes (GATv2 attention, shared by conv1/conv2).
__global__ void edge_logits(const int* __restrict__ ei, const float* __restrict__ xl,
                            const float* __restrict__ xr, const float* __restrict__ att,
                            float* __restrict__ logits, int* __restrict__ mkey){
  int e = blockIdx.x*blockDim.x + threadIdx.x;
  if (e >= NEDGE + NNODE) return;
  int sN, dN;
  if (e < NEDGE) { sN = ei[e]; dN = ei[NEDGE + e]; } else { sN = dN = e - NEDGE; }
  const float4 a0 = *(const float4*)(xl + sN*8);
  const float4 a1 = *(const float4*)(xl + sN*8 + 4);
  const float4 b0 = *(const float4*)(xr + dN*8);
  const float4 b1 = *(const float4*)(xr + dN*8 + 4);
  float l0 = att[0]*lrelu(a0.x+b0.x) + att[1]*lrelu(a0.y+b0.y)
           + att[2]*lrelu(a0.z+b0.z) + att[3]*lrelu(a0.w+b0.w);
  float l1 = att[4]*lrelu(a1.x+b1.x) + att[5]*lrelu(a1.y+b1.y)
           + att[6]*lrelu(a1.z+b1.z) + att[7]*lrelu(a1.w+b1.w);
  logits[e*2]   = l0;
  logits[e*2+1] = l1;
  atomicMax(mkey + dN*2,     fkey(l0));
  atomicMax(mkey + dN*2 + 1, fkey(l1));
}

__global__ void edge_denom(const int* __restrict__ ei, const float* __restrict__ logits,
                           const int* __restrict__ mkey, float* __restrict__ denom){
  int e = blockIdx.x*blockDim.x + threadIdx.x;
  if (e >= NEDGE + NNODE) return;
  int dN = (e < NEDGE) ? ei[NEDGE + e] : e - NEDGE;
  atomicAdd(denom + dN*2,     expf(logits[e*2]   - fdec(mkey[dN*2])));
  atomicAdd(denom + dN*2 + 1, expf(logits[e*2+1] - fdec(mkey[dN*2 + 1])));
}

__global__ void edge_accum(const int* __restrict__ ei, const float* __restrict__ logits,
                           const int* __restrict__ mkey, const float* __restrict__ denom,
                           const float* __restrict__ xl, float* __restrict__ gat){
  int e = blockIdx.x*blockDim.x + threadIdx.x;
  if (e >= NEDGE + NNODE) return;
  int sN, dN;
  if (e < NEDGE) { sN = ei[e]; dN = ei[NEDGE + e]; } else { sN = dN = e - NEDGE; }
  float al0 = expf(logits[e*2]   - fdec(mkey[dN*2]))     / (denom[dN*2]     + 1e-16f);
  float al1 = expf(logits[e*2+1] - fdec(mkey[dN*2 + 1])) / (denom[dN*2 + 1] + 1e-16f);
  const float4 a0 = *(const float4*)(xl + sN*8);
  const float4 a1 = *(const float4*)(xl + sN*8 + 4);
  atomicAdd(gat + dN*8 + 0, a0.x*al0);
  atomicAdd(gat + dN*8 + 1, a0.y*al0);
  atomicAdd(gat + dN*8 + 2, a0.z*al0);
  atomicAdd(gat + dN*8 + 3, a0.w*al0);
  atomicAdd(gat + dN*8 + 4, a1.x*al1);
  atomicAdd(gat + dN*8 + 5, a1.y*al1);
  atomicAdd(gat + dN*8 + 6, a1.z*al1);
  atomicAdd(gat + dN*8 + 7, a1.w*al1);
}

// ---------------------------------------------------------------------------
// x1 = relu(gat1+bias1)@lin1_W + lin1_b ; also xl2/xr2 = x1*W{l,r}2 + b{l,r}2
__global__ void node_x1(const float* __restrict__ gat, const float* __restrict__ bias1,
                        const float* __restrict__ linW, const float* __restrict__ linb,
                        const float* __restrict__ Wl2, const float* __restrict__ bl2,
                        const float* __restrict__ Wr2, const float* __restrict__ br2,
                        float* __restrict__ x1, float* __restrict__ xl2,
                        float* __restrict__ xr2){
  int n = blockIdx.x*blockDim.x + threadIdx.x;
  if (n >= NNODE) return;
  float sacc = linb[0];
  #pragma unroll
  for (int c = 0; c < 8; ++c)
    sacc = fmaf(frelu(gat[n*8+c] + bias1[c]), linW[c], sacc);
  x1[n] = sacc;
  #pragma unroll
  for (int c = 0; c < 8; ++c) {
    xl2[n*8+c] = fmaf(sacc, Wl2[c], bl2[c]);
    xr2[n*8+c] = fmaf(sacc, Wr2[c], br2[c]);
  }
}

__global__ void node_x2(const float* __restrict__ gat, const float* __restrict__ bias2,
                        const float* __restrict__ linW, const float* __restrict__ linb,
                        float* __restrict__ x2){
  int n = blockIdx.x*blockDim.x + threadIdx.x;
  if (n >= NNODE) return;
  float sacc = linb[0];
  #pragma unroll
  for (int c = 0; c < 8; ++c)
    sacc = fmaf(frelu(gat[n*8+c] + bias2[c]), linW[c], sacc);
  x2[n] = sacc;
}

// ---------------------------------------------------------------------------
// h1 = relu(encp + x1*W1[9998] + x2*W1[9999] + b1); h2 = relu(h1@W2+b2);
// out = h2@W3 + b3.  One node per wave.
__global__ void enc_finish(const float* __restrict__ encp, const float* __restrict__ x1,
                           const float* __restrict__ x2, const float* __restrict__ W1,
                           const float* __restrict__ b1, const float* __restrict__ W2,
                           const float* __restrict__ b2, const float* __restrict__ W3,
                           const float* __restrict__ b3, float* __restrict__ out){
  __shared__ float hb[4][64];
  int wv = threadIdx.x >> 6, lane = threadIdx.x & 63;
  int n = blockIdx.x*4 + wv;
  float hv = encp[n*64 + lane] + x1[n]*W1[9998*64 + lane]
           + x2[n]*W1[9999*64 + lane] + b1[lane];
  hb[wv][lane] = frelu(hv);
  __syncthreads();
  float t = 0.f;
  if (lane < 32) {
    float a2 = b2[lane];
    #pragma unroll
    for (int k = 0; k < 64; ++k) a2 = fmaf(hb[wv][k], W2[k*32 + lane], a2);
    t = frelu(a2) * W3[lane];
  }
  #pragma unroll
  for (int m = 1; m < 64; m <<= 1) t += __shfl_xor(t, m, 64);
  if (lane == 0) out[n] = t + b3[0];
}

// ---------------------------------------------------------------------------
extern "C" void kernel_launch(void* const* d_in, const int* in_sizes, int n_in,
                              void* d_out, int out_size, void* d_ws, size_t ws_size,
                              hipStream_t stream){
  (void)in_sizes; (void)n_in; (void)out_size; (void)ws_size;
  const float* x    = (const float*)d_in[0];
  const int*   ei   = (const int*)  d_in[1];
  const float* Wl1  = (const float*)d_in[2];
  const float* bl1  = (const float*)d_in[3];
  const float* Wr1  = (const float*)d_in[4];
  const float* br1  = (const float*)d_in[5];
  const float* att1 = (const float*)d_in[6];
  const float* bias1= (const float*)d_in[7];
  const float* l1W  = (const float*)d_in[8];
  const float* l1b  = (const float*)d_in[9];
  const float* Wl2  = (const float*)d_in[10];
  const float* bl2  = (const float*)d_in[11];
  const float* Wr2  = (const float*)d_in[12];
  const float* br2  = (const float*)d_in[13];
  const float* att2 = (const float*)d_in[14];
  const float* bias2= (const float*)d_in[15];
  const float* l2W  = (const float*)d_in[16];
  const float* l2b  = (const float*)d_in[17];
  const float* eW1  = (const float*)d_in[18];
  const float* eb1  = (const float*)d_in[19];
  const float* eW2  = (const float*)d_in[20];
  const float* eb2  = (const float*)d_in[21];
  const float* eW3  = (const float*)d_in[22];
  const float* eb3  = (const float*)d_in[23];

  float* ws = (float*)d_ws;
  size_t off = 0;
  auto alloc = [&](size_t nel){ float* pp = ws + off; off += (nel + 63) & ~size_t(63); return pp; };
  float* WT     = alloc((size_t)80*KPAD);
  float* xl1    = alloc(NNODE*8);
  float* xr1    = alloc(NNODE*8);
  float* encp   = alloc(NNODE*64);
  float* logits = alloc((size_t)(NEDGE+NNODE)*2);
  float* denom  = alloc(NNODE*2);
  float* gat    = alloc(NNODE*8);
  float* x1a    = alloc(NNODE);
  float* x2a    = alloc(NNODE);
  float* xl2    = alloc(NNODE*8);
  float* xr2    = alloc(NNODE*8);
  int*   mkey   = (int*)alloc(NNODE*2);

  const int ET = NEDGE + NNODE;
  const int eb = (ET + 255)/256;
  const int nb = (NNODE*8 + 255)/256;

  prep_wt<<<(80*KPAD + 255)/256, 256, 0, stream>>>(Wl1, Wr1, eW1, WT);

  hipMemsetAsync(xl1,  0, NNODE*8*sizeof(float), stream);
  hipMemsetAsync(xr1,  0, NNODE*8*sizeof(float), stream);
  hipMemsetAsync(encp, 0, NNODE*64*sizeof(float), stream);
  k1_fused<<<1252, 512, 0, stream>>>(x, WT, bl1, br1, xl1, xr1, encp);

  // conv1 attention
  init_conv<<<nb, 256, 0, stream>>>(mkey, denom, gat);
  edge_logits<<<eb, 256, 0, stream>>>(ei, xl1, xr1, att1, logits, mkey);
  edge_denom <<<eb, 256, 0, stream>>>(ei, logits, mkey, denom);
  edge_accum <<<eb, 256, 0, stream>>>(ei, logits, mkey, denom, xl1, gat);
  node_x1<<<(NNODE+255)/256, 256, 0, stream>>>(gat, bias1, l1W, l1b, Wl2, bl2, Wr2, br2,
                                               x1a, xl2, xr2);

  // conv2 attention
  init_conv<<<nb, 256, 0, stream>>>(mkey, denom, gat);
  edge_logits<<<eb, 256, 0, stream>>>(ei, xl2, xr2, att2, logits, mkey);
  edge_denom <<<eb, 256, 0, stream>>>(ei, logits, mkey, denom);
  edge_accum <<<eb, 256, 0, stream>>>(ei, logits, mkey, denom, xl2, gat);
  node_x2<<<(NNODE+255)/256, 256, 0, stream>>>(gat, bias2, l2W, l2b, x2a);

  enc_finish<<<NNODE/4, 256, 0, stream>>>(encp, x1a, x2a, eW1, eb1, eW2, eb2, eW3, eb3,
                                          (float*)d_out);
}

// Round 3
// 800.349 us; speedup vs baseline: 1.3889x; 1.3889x over previous
//
#include <hip/hip_runtime.h>
#include <math.h>

#define NNODE 10000
#define INCH  9998
#define NEDGE 320000
#define KC    128
#define KPAD  10240
#define NCHH  40          // chunks per K-half (2 halves * 40 * 128 = 10240)

__device__ __forceinline__ float lrelu(float v){ return v > 0.f ? v : 0.2f*v; }
__device__ __forceinline__ float frelu(float v){ return v > 0.f ? v : 0.f; }

#define GLOAD_LDS16(g, l) __builtin_amdgcn_global_load_lds( \
    (const __attribute__((address_space(1))) unsigned int*)(g), \
    (__attribute__((address_space(3))) unsigned int*)(l), 16, 0, 0)

// ---------------------------------------------------------------------------
// WT[c][k] = Wcat[k][c], zero-padded to KPAD. c: 0..7 Wl1, 8..15 Wr1, 16..79 enc_W1.
__global__ void prep_wt(const float* __restrict__ Wl, const float* __restrict__ Wr,
                        const float* __restrict__ We, float* __restrict__ WT){
  int idx = blockIdx.x*256 + threadIdx.x;
  if (idx >= 80*KPAD) return;
  int c = idx / KPAD;
  int k = idx - c*KPAD;
  float v = 0.f;
  if (k < INCH)
    v = (c < 8) ? Wl[k*8 + c] : (c < 16 ? Wr[k*8 + (c-8)] : We[k*64 + (c-16)]);
  WT[idx] = v;
}

// ---------------------------------------------------------------------------
// Fused 80-col GEMM over x. Grid: 1250 = 625 row-slices (16 rows) x 2 K-halves.
// Block: 1024 thr = 16 waves = 4 rowgroups(4 rows/lane) x 4 colgroups(20 cols).
// acc[4][20] = 80 VGPR/lane (fits the 128-VGPR cap at 4 waves/SIMD -> no spill).
// W chunk (80x128 = 40KB) double-buffered via global_load_lds; x float2/lane.
__global__ __launch_bounds__(1024, 4)
void k1_fused(const float* __restrict__ x, const float* __restrict__ WT,
              const float* __restrict__ bl1, const float* __restrict__ br1,
              float* __restrict__ xl1, float* __restrict__ xr1,
              float* __restrict__ encp){
  __shared__ float lds[2][80*KC];
  const int tid  = threadIdx.x;
  const int lane = tid & 63;
  const int w    = tid >> 6;     // 0..15
  const int cg   = w & 3;        // colgroup: cols cg*20..+19
  const int rg   = w >> 2;       // rowgroup: rows rg*4..+3
  const int sid  = blockIdx.x;
  const int kh   = sid & 1;      // K half
  const int rs   = sid >> 1;     // row slice 0..624 (rows rs*16..+15)
  const int ch0  = kh*NCHH;
  const int maxi = NNODE*INCH - 2;

  // stage W chunk ch0 into buffer 0 (async; 40 segs of 1KB, wave-uniform dest)
  {
    const int k0 = ch0*KC;
    #pragma unroll
    for (int i = 0; i < 3; ++i) {
      int seg = w + 16*i;
      if (seg < 40) {
        const float* gp = WT + (size_t)(2*seg + (lane>>5))*KPAD + k0 + ((lane&31)<<2);
        GLOAD_LDS16(gp, &lds[0][0] + seg*256);
      }
    }
  }

  float acc[4][20];
  #pragma unroll
  for (int r = 0; r < 4; ++r)
    #pragma unroll
    for (int c = 0; c < 20; ++c) acc[r][c] = 0.f;

  // prefetch x for first chunk
  float2 xn[4];
  #pragma unroll
  for (int r = 0; r < 4; ++r) {
    int rw = rs*16 + rg*4 + r;
    int xi = rw*INCH + ch0*KC + (lane<<1);
    xi = min(xi, maxi);                       // K-pad region: W is zero there
    xn[r] = *(const float2*)(x + xi);
  }

  for (int ci = 0; ci < NCHH; ++ci) {
    const int cur = ci & 1;
    __syncthreads();   // compiler drains vmcnt(0): buf[cur] staged, xn landed

    if (ci + 1 < NCHH) {            // async-stage next chunk into other buffer
      const int k0n = (ch0 + ci + 1)*KC;
      #pragma unroll
      for (int i = 0; i < 3; ++i) {
        int seg = w + 16*i;
        if (seg < 40) {
          const float* gp = WT + (size_t)(2*seg + (lane>>5))*KPAD + k0n + ((lane&31)<<2);
          GLOAD_LDS16(gp, &lds[cur^1][0] + seg*256);
        }
      }
    }

    float2 xv[4];
    #pragma unroll
    for (int r = 0; r < 4; ++r) xv[r] = xn[r];
    if (ci + 1 < NCHH) {            // prefetch next chunk's x (overlaps FMA)
      const int k0n = (ch0 + ci + 1)*KC;
      #pragma unroll
      for (int r = 0; r < 4; ++r) {
        int rw = rs*16 + rg*4 + r;
        int xi = rw*INCH + k0n + (lane<<1);
        xi = min(xi, maxi);
        xn[r] = *(const float2*)(x + xi);
      }
    }

    const float* wl = &lds[cur][0] + cg*20*KC + (lane<<1);
    #pragma unroll
    for (int cs = 0; cs < 20; ++cs) {
      float2 wv = *(const float2*)(wl + cs*KC);   // b64, 2-way bank alias = free
      #pragma unroll
      for (int r = 0; r < 4; ++r) {
        acc[r][cs] = fmaf(xv[r].x, wv.x, acc[r][cs]);
        acc[r][cs] = fmaf(xv[r].y, wv.y, acc[r][cs]);
      }
    }
  }

  // 64-lane butterfly reduce over the k-stripes
  #pragma unroll
  for (int m = 1; m < 64; m <<= 1)
    #pragma unroll
    for (int r = 0; r < 4; ++r)
      #pragma unroll
      for (int cs = 0; cs < 20; ++cs)
        acc[r][cs] += __shfl_xor(acc[r][cs], m, 64);

  float vout[2];
  vout[0] = 0.f; vout[1] = 0.f;
  #pragma unroll
  for (int o = 0; o < 80; ++o)
    if ((o & 63) == lane) vout[o >> 6] = acc[o/20][o%20];   // static indices

  #pragma unroll
  for (int t = 0; t < 2; ++t) {
    int o = lane + (t << 6);
    if (o < 80) {
      int r  = o / 20;
      int cs = o - r*20;
      int rw = rs*16 + rg*4 + r;
      int col = cg*20 + cs;
      float val = vout[t];
      if (kh == 0) {
        if (col < 8)       val += bl1[col];
        else if (col < 16) val += br1[col - 8];
      }
      if (col < 8)       atomicAdd(xl1 + rw*8 + col, val);
      else if (col < 16) atomicAdd(xr1 + rw*8 + col - 8, val);
      else               atomicAdd(encp + rw*64 + col - 16, val);
    }
  }
}

// ---------------------------------------------------------------------------
// conv1 edge pass A: logits -> exp -> store + denom. (No max subtraction:
// logits ~ N(0,1.4), |l| < ~10, exp is safe in fp32; softmax is shift-invariant.)
__global__ void edgeA1(const int* __restrict__ ei, const float* __restrict__ xl,
                       const float* __restrict__ xr, const float* __restrict__ att,
                       float* __restrict__ elog, float* __restrict__ denom){
  int e = blockIdx.x*blockDim.x + threadIdx.x;
  if (e >= NEDGE + NNODE) return;
  int sN, dN;
  if (e < NEDGE) { sN = ei[e]; dN = ei[NEDGE + e]; } else { sN = dN = e - NEDGE; }
  const float4 a0 = *(const float4*)(xl + sN*8);
  const float4 a1 = *(const float4*)(xl + sN*8 + 4);
  const float4 b0 = *(const float4*)(xr + dN*8);
  const float4 b1 = *(const float4*)(xr + dN*8 + 4);
  float l0 = att[0]*lrelu(a0.x+b0.x) + att[1]*lrelu(a0.y+b0.y)
           + att[2]*lrelu(a0.z+b0.z) + att[3]*lrelu(a0.w+b0.w);
  float l1 = att[4]*lrelu(a1.x+b1.x) + att[5]*lrelu(a1.y+b1.y)
           + att[6]*lrelu(a1.z+b1.z) + att[7]*lrelu(a1.w+b1.w);
  float e0 = expf(l0), e1 = expf(l1);
  elog[e*2]   = e0;
  elog[e*2+1] = e1;
  atomicAdd(denom + dN*2,     e0);
  atomicAdd(denom + dN*2 + 1, e1);
}

__global__ void edgeB1(const int* __restrict__ ei, const float* __restrict__ elog,
                       const float* __restrict__ denom, const float* __restrict__ xl,
                       float* __restrict__ gat){
  int e = blockIdx.x*blockDim.x + threadIdx.x;
  if (e >= NEDGE + NNODE) return;
  int sN, dN;
  if (e < NEDGE) { sN = ei[e]; dN = ei[NEDGE + e]; } else { sN = dN = e - NEDGE; }
  float al0 = elog[e*2]   / denom[dN*2];
  float al1 = elog[e*2+1] / denom[dN*2 + 1];
  const float4 a0 = *(const float4*)(xl + sN*8);
  const float4 a1 = *(const float4*)(xl + sN*8 + 4);
  atomicAdd(gat + dN*8 + 0, a0.x*al0);
  atomicAdd(gat + dN*8 + 1, a0.y*al0);
  atomicAdd(gat + dN*8 + 2, a0.z*al0);
  atomicAdd(gat + dN*8 + 3, a0.w*al0);
  atomicAdd(gat + dN*8 + 4, a1.x*al1);
  atomicAdd(gat + dN*8 + 5, a1.y*al1);
  atomicAdd(gat + dN*8 + 6, a1.z*al1);
  atomicAdd(gat + dN*8 + 7, a1.w*al1);
}

// x1 = relu(gat1+bias1)@lin1_W + lin1_b
__global__ void node_x1(const float* __restrict__ gat, const float* __restrict__ bias1,
                        const float* __restrict__ linW, const float* __restrict__ linb,
                        float* __restrict__ x1){
  int n = blockIdx.x*blockDim.x + threadIdx.x;
  if (n >= NNODE) return;
  float sacc = linb[0];
  #pragma unroll
  for (int c = 0; c < 8; ++c)
    sacc = fmaf(frelu(gat[n*8+c] + bias1[c]), linW[c], sacc);
  x1[n] = sacc;
}

// conv2 is rank-1: xl2/xr2 are recomputed from the scalar x1 per endpoint.
__global__ void edgeA2(const int* __restrict__ ei, const float* __restrict__ x1,
                       const float* __restrict__ Wl2, const float* __restrict__ bl2,
                       const float* __restrict__ Wr2, const float* __restrict__ br2,
                       const float* __restrict__ att,
                       float* __restrict__ elog, float* __restrict__ denom){
  int e = blockIdx.x*blockDim.x + threadIdx.x;
  if (e >= NEDGE + NNODE) return;
  int sN, dN;
  if (e < NEDGE) { sN = ei[e]; dN = ei[NEDGE + e]; } else { sN = dN = e - NEDGE; }
  float xs = x1[sN], xd = x1[dN];
  float l0 = 0.f, l1 = 0.f;
  #pragma unroll
  for (int c = 0; c < 4; ++c) {
    l0 = fmaf(att[c],   lrelu(fmaf(xs, Wl2[c],   bl2[c])   + fmaf(xd, Wr2[c],   br2[c])),   l0);
    l1 = fmaf(att[4+c], lrelu(fmaf(xs, Wl2[4+c], bl2[4+c]) + fmaf(xd, Wr2[4+c], br2[4+c])), l1);
  }
  float e0 = expf(l0), e1 = expf(l1);
  elog[e*2]   = e0;
  elog[e*2+1] = e1;
  atomicAdd(denom + dN*2,     e0);
  atomicAdd(denom + dN*2 + 1, e1);
}

__global__ void edgeB2(const int* __restrict__ ei, const float* __restrict__ elog,
                       const float* __restrict__ denom, const float* __restrict__ x1,
                       const float* __restrict__ Wl2, const float* __restrict__ bl2,
                       float* __restrict__ gat){
  int e = blockIdx.x*blockDim.x + threadIdx.x;
  if (e >= NEDGE + NNODE) return;
  int sN, dN;
  if (e < NEDGE) { sN = ei[e]; dN = ei[NEDGE + e]; } else { sN = dN = e - NEDGE; }
  float al0 = elog[e*2]   / denom[dN*2];
  float al1 = elog[e*2+1] / denom[dN*2 + 1];
  float xs = x1[sN];
  #pragma unroll
  for (int c = 0; c < 4; ++c) {
    atomicAdd(gat + dN*8 + c,     fmaf(xs, Wl2[c],   bl2[c])  *al0);
    atomicAdd(gat + dN*8 + 4 + c, fmaf(xs, Wl2[4+c], bl2[4+c])*al1);
  }
}

// ---------------------------------------------------------------------------
// x2 inline; h1 = relu(encp + x1*W1[9998] + x2*W1[9999] + b1);
// h2 = relu(h1@W2+b2); out = h2@W3 + b3.  One node per wave.
__global__ void enc_finish(const float* __restrict__ encp, const float* __restrict__ x1,
                           const float* __restrict__ gat2, const float* __restrict__ bias2,
                           const float* __restrict__ l2W, const float* __restrict__ l2b,
                           const float* __restrict__ W1, const float* __restrict__ b1,
                           const float* __restrict__ W2, const float* __restrict__ b2,
                           const float* __restrict__ W3, const float* __restrict__ b3,
                           float* __restrict__ out){
  __shared__ float hb[4][64];
  int wv = threadIdx.x >> 6, lane = threadIdx.x & 63;
  int n = blockIdx.x*4 + wv;
  float x2v = l2b[0];
  #pragma unroll
  for (int c = 0; c < 8; ++c)
    x2v = fmaf(frelu(gat2[n*8+c] + bias2[c]), l2W[c], x2v);
  float hv = encp[n*64 + lane] + x1[n]*W1[9998*64 + lane]
           + x2v*W1[9999*64 + lane] + b1[lane];
  hb[wv][lane] = frelu(hv);
  __syncthreads();
  float t = 0.f;
  if (lane < 32) {
    float a2 = b2[lane];
    #pragma unroll
    for (int k = 0; k < 64; ++k) a2 = fmaf(hb[wv][k], W2[k*32 + lane], a2);
    t = frelu(a2) * W3[lane];
  }
  #pragma unroll
  for (int m = 1; m < 64; m <<= 1) t += __shfl_xor(t, m, 64);
  if (lane == 0) out[n] = t + b3[0];
}

// ---------------------------------------------------------------------------
extern "C" void kernel_launch(void* const* d_in, const int* in_sizes, int n_in,
                              void* d_out, int out_size, void* d_ws, size_t ws_size,
                              hipStream_t stream){
  (void)in_sizes; (void)n_in; (void)out_size; (void)ws_size;
  const float* x    = (const float*)d_in[0];
  const int*   ei   = (const int*)  d_in[1];
  const float* Wl1  = (const float*)d_in[2];
  const float* bl1  = (const float*)d_in[3];
  const float* Wr1  = (const float*)d_in[4];
  const float* br1  = (const float*)d_in[5];
  const float* att1 = (const float*)d_in[6];
  const float* bias1= (const float*)d_in[7];
  const float* l1W  = (const float*)d_in[8];
  const float* l1b  = (const float*)d_in[9];
  const float* Wl2  = (const float*)d_in[10];
  const float* bl2  = (const float*)d_in[11];
  const float* Wr2  = (const float*)d_in[12];
  const float* br2  = (const float*)d_in[13];
  const float* att2 = (const float*)d_in[14];
  const float* bias2= (const float*)d_in[15];
  const float* l2W  = (const float*)d_in[16];
  const float* l2b  = (const float*)d_in[17];
  const float* eW1  = (const float*)d_in[18];
  const float* eb1  = (const float*)d_in[19];
  const float* eW2  = (const float*)d_in[20];
  const float* eb2  = (const float*)d_in[21];
  const float* eW3  = (const float*)d_in[22];
  const float* eb3  = (const float*)d_in[23];

  float* ws = (float*)d_ws;
  size_t off = 0;
  auto alloc = [&](size_t nel){ float* pp = ws + off; off += (nel + 63) & ~size_t(63); return pp; };
  float* WT     = alloc((size_t)80*KPAD);
  float* elog   = alloc((size_t)(NEDGE+NNODE)*2);
  // contiguous zero block [xl1 .. gat2]:
  float* xl1    = alloc(NNODE*8);
  float* xr1    = alloc(NNODE*8);
  float* encp   = alloc(NNODE*64);
  float* denom1 = alloc(NNODE*2);
  float* gat1   = alloc(NNODE*8);
  float* denom2 = alloc(NNODE*2);
  float* gat2   = alloc(NNODE*8);
  size_t zspan  = (size_t)((gat2 + ((NNODE*8 + 63) & ~63)) - xl1) * sizeof(float);
  float* x1a    = alloc(NNODE);

  const int ET = NEDGE + NNODE;
  const int eb = (ET + 255)/256;

  prep_wt<<<(80*KPAD + 255)/256, 256, 0, stream>>>(Wl1, Wr1, eW1, WT);
  hipMemsetAsync(xl1, 0, zspan, stream);

  k1_fused<<<1250, 1024, 0, stream>>>(x, WT, bl1, br1, xl1, xr1, encp);

  edgeA1<<<eb, 256, 0, stream>>>(ei, xl1, xr1, att1, elog, denom1);
  edgeB1<<<eb, 256, 0, stream>>>(ei, elog, denom1, xl1, gat1);
  node_x1<<<(NNODE+255)/256, 256, 0, stream>>>(gat1, bias1, l1W, l1b, x1a);

  edgeA2<<<eb, 256, 0, stream>>>(ei, x1a, Wl2, bl2, Wr2, br2, att2, elog, denom2);
  edgeB2<<<eb, 256, 0, stream>>>(ei, elog, denom2, x1a, Wl2, bl2, gat2);

  enc_finish<<<NNODE/4, 256, 0, stream>>>(encp, x1a, gat2, bias2, l2W, l2b,
                                          eW1, eb1, eW2, eb2, eW3, eb3,
                                          (float*)d_out);
}

// Round 4
// 719.554 us; speedup vs baseline: 1.5448x; 1.1123x over previous
//
#include <hip/hip_runtime.h>
#include <math.h>

#define NNODE 10000
#define INCH  9998
#define NEDGE 320000
#define KPADW 10240        // padded K for weight arrays
#define KSPLIT 4
#define KRANGE 2560        // K per block = KPADW/KSPLIT
#define NCH   40           // chunks per block (64 k each)

typedef _Float16 half8 __attribute__((ext_vector_type(8)));
typedef float    f32x4 __attribute__((ext_vector_type(4)));

__device__ __forceinline__ float lrelu(float v){ return v > 0.f ? v : 0.2f*v; }
__device__ __forceinline__ float frelu(float v){ return v > 0.f ? v : 0.f; }

// ---------------------------------------------------------------------------
// Weight prep: WhT/WlT[col][k] fp16 hi + 2048-scaled residual, col-major-K,
// zero-padded to KPADW. col: 0..7 Wl1, 8..15 Wr1, 16..79 enc_W1.
__global__ void prep_wt(const float* __restrict__ Wl, const float* __restrict__ Wr,
                        const float* __restrict__ We, _Float16* __restrict__ WhT,
                        _Float16* __restrict__ WlT){
  int idx = blockIdx.x*256 + threadIdx.x;
  if (idx >= 80*KPADW) return;
  int col = idx / KPADW;
  int k   = idx - col*KPADW;
  float v = 0.f;
  if (k < INCH)
    v = (col < 8) ? Wl[k*8 + col] : (col < 16 ? Wr[k*8 + (col-8)] : We[k*64 + (col-16)]);
  _Float16 h = (_Float16)v;
  _Float16 l = (_Float16)((v - (float)h) * 2048.f);
  WhT[idx] = h;
  WlT[idx] = l;
}

// ---------------------------------------------------------------------------
// Fused 80-col GEMM over x via mfma_f32_16x16x32_f16, split-fp16 (hi+lo/2048).
// Grid: 628 = 157 row-blocks (64 rows) x 4 K-splits. Block: 256 thr = 4 waves,
// each wave owns 16 rows x 80 cols (5 MFMA col-tiles), K-range 2560.
// W hi/lo staged per-64k-chunk in LDS (reg-staged, padded stride 68 halves).
__global__ __launch_bounds__(256, 3)
void k1_fused(const float* __restrict__ x, const _Float16* __restrict__ WhT,
              const _Float16* __restrict__ WlT, const float* __restrict__ bl1,
              const float* __restrict__ br1, float* __restrict__ xl1,
              float* __restrict__ xr1, float* __restrict__ encp){
  __shared__ _Float16 lds[2][80][68];   // [hi/lo][col][64k + 4 pad]
  const int tid  = threadIdx.x;
  const int lane = tid & 63;
  const int wv   = tid >> 6;            // 0..3
  const int g    = lane >> 4;           // k-group 0..3
  const int c0   = lane & 15;
  const int kh   = blockIdx.x & 3;
  const int rb   = blockIdx.x >> 2;     // 0..156
  const int k0b  = kh*KRANGE;
  const int maxi = NNODE*INCH - 2;

  const int arow  = rb*64 + wv*16 + c0;           // A-fragment row (this lane)
  const int arowc = arow < NNODE ? arow : NNODE-1;
  const int xbase = arowc*INCH;

  f32x4 acc_hi[5], acc_lo[5];
  #pragma unroll
  for (int t = 0; t < 5; ++t){
    acc_hi[t] = (f32x4)0.f;
    acc_lo[t] = (f32x4)0.f;
  }

  uint4 wreg[5];
  int scol[5], sks[5], ssp[5];
  #pragma unroll
  for (int i = 0; i < 5; ++i){
    int sg = tid + 256*i;               // 0..1279 : 16B segments
    int sp = sg >= 640 ? 1 : 0;
    int s2 = sg - sp*640;
    ssp[i] = sp; scol[i] = s2 >> 3; sks[i] = s2 & 7;
  }

  // load stage for chunk 0
  #pragma unroll
  for (int i = 0; i < 5; ++i){
    const _Float16* src = (ssp[i] ? WlT : WhT) + scol[i]*KPADW + k0b + sks[i]*8;
    wreg[i] = *(const uint4*)src;
  }

  for (int c = 0; c < NCH; ++c){
    __syncthreads();                    // readers done with lds
    #pragma unroll
    for (int i = 0; i < 5; ++i)
      *(uint4*)&lds[ssp[i]][scol[i]][sks[i]*8] = wreg[i];
    if (c + 1 < NCH){                   // issue next chunk's global loads
      const int k0n = k0b + (c+1)*64;
      #pragma unroll
      for (int i = 0; i < 5; ++i){
        const _Float16* src = (ssp[i] ? WlT : WhT) + scol[i]*KPADW + k0n + sks[i]*8;
        wreg[i] = *(const uint4*)src;
      }
    }
    __syncthreads();                    // lds visible

    #pragma unroll
    for (int s = 0; s < 2; ++s){        // two K-steps of 32
      const int kb = k0b + c*64 + s*32 + 8*g;
      float2 f0 = *(const float2*)(x + min(xbase + kb,     maxi));
      float2 f1 = *(const float2*)(x + min(xbase + kb + 2, maxi));
      float2 f2 = *(const float2*)(x + min(xbase + kb + 4, maxi));
      float2 f3 = *(const float2*)(x + min(xbase + kb + 6, maxi));
      float xf[8] = {f0.x, f0.y, f1.x, f1.y, f2.x, f2.y, f3.x, f3.y};
      half8 ah, al;
      #pragma unroll
      for (int j = 0; j < 8; ++j){
        _Float16 h = (_Float16)xf[j];
        ah[j] = h;
        al[j] = (_Float16)((xf[j] - (float)h) * 2048.f);
      }
      #pragma unroll
      for (int t = 0; t < 5; ++t){
        half8 bh = *(const half8*)&lds[0][c0 + 16*t][s*32 + g*8];
        half8 bl = *(const half8*)&lds[1][c0 + 16*t][s*32 + g*8];
        acc_hi[t] = __builtin_amdgcn_mfma_f32_16x16x32_f16(ah, bh, acc_hi[t], 0, 0, 0);
        acc_lo[t] = __builtin_amdgcn_mfma_f32_16x16x32_f16(ah, bl, acc_lo[t], 0, 0, 0);
        acc_lo[t] = __builtin_amdgcn_mfma_f32_16x16x32_f16(al, bh, acc_lo[t], 0, 0, 0);
      }
    }
  }

  // epilogue: C/D layout col=lane&15, row=4*(lane>>4)+reg  [m89-verified]
  const float inv2048 = 4.8828125e-4f;
  const int nodeb = rb*64 + wv*16 + 4*g;
  #pragma unroll
  for (int t = 0; t < 5; ++t){
    #pragma unroll
    for (int r = 0; r < 4; ++r){
      int node = nodeb + r;
      if (node < NNODE){
        int col = 16*t + c0;
        float val = acc_hi[t][r] + acc_lo[t][r]*inv2048;
        if (kh == 0){
          if (col < 8)       val += bl1[col];
          else if (col < 16) val += br1[col - 8];
        }
        if (col < 8)       atomicAdd(xl1 + node*8 + col, val);
        else if (col < 16) atomicAdd(xr1 + node*8 + col - 8, val);
        else               atomicAdd(encp + node*64 + col - 16, val);
      }
    }
  }
}

// ---------------------------------------------------------------------------
// conv1 edge pass A: logits -> exp -> store + denom. (No max subtraction:
// logits are O(1); exp safe in fp32; softmax is shift-invariant.)
__global__ void edgeA1(const int* __restrict__ ei, const float* __restrict__ xl,
                       const float* __restrict__ xr, const float* __restrict__ att,
                       float* __restrict__ elog, float* __restrict__ denom){
  int e = blockIdx.x*blockDim.x + threadIdx.x;
  if (e >= NEDGE + NNODE) return;
  int sN, dN;
  if (e < NEDGE) { sN = ei[e]; dN = ei[NEDGE + e]; } else { sN = dN = e - NEDGE; }
  const float4 a0 = *(const float4*)(xl + sN*8);
  const float4 a1 = *(const float4*)(xl + sN*8 + 4);
  const float4 b0 = *(const float4*)(xr + dN*8);
  const float4 b1 = *(const float4*)(xr + dN*8 + 4);
  float l0 = att[0]*lrelu(a0.x+b0.x) + att[1]*lrelu(a0.y+b0.y)
           + att[2]*lrelu(a0.z+b0.z) + att[3]*lrelu(a0.w+b0.w);
  float l1 = att[4]*lrelu(a1.x+b1.x) + att[5]*lrelu(a1.y+b1.y)
           + att[6]*lrelu(a1.z+b1.z) + att[7]*lrelu(a1.w+b1.w);
  float e0 = expf(l0), e1 = expf(l1);
  elog[e*2]   = e0;
  elog[e*2+1] = e1;
  atomicAdd(denom + dN*2,     e0);
  atomicAdd(denom + dN*2 + 1, e1);
}

__global__ void edgeB1(const int* __restrict__ ei, const float* __restrict__ elog,
                       const float* __restrict__ denom, const float* __restrict__ xl,
                       float* __restrict__ gat){
  int e = blockIdx.x*blockDim.x + threadIdx.x;
  if (e >= NEDGE + NNODE) return;
  int sN, dN;
  if (e < NEDGE) { sN = ei[e]; dN = ei[NEDGE + e]; } else { sN = dN = e - NEDGE; }
  float al0 = elog[e*2]   / denom[dN*2];
  float al1 = elog[e*2+1] / denom[dN*2 + 1];
  const float4 a0 = *(const float4*)(xl + sN*8);
  const float4 a1 = *(const float4*)(xl + sN*8 + 4);
  atomicAdd(gat + dN*8 + 0, a0.x*al0);
  atomicAdd(gat + dN*8 + 1, a0.y*al0);
  atomicAdd(gat + dN*8 + 2, a0.z*al0);
  atomicAdd(gat + dN*8 + 3, a0.w*al0);
  atomicAdd(gat + dN*8 + 4, a1.x*al1);
  atomicAdd(gat + dN*8 + 5, a1.y*al1);
  atomicAdd(gat + dN*8 + 6, a1.z*al1);
  atomicAdd(gat + dN*8 + 7, a1.w*al1);
}

// x1 = relu(gat1+bias1)@lin1_W + lin1_b
__global__ void node_x1(const float* __restrict__ gat, const float* __restrict__ bias1,
                        const float* __restrict__ linW, const float* __restrict__ linb,
                        float* __restrict__ x1){
  int n = blockIdx.x*blockDim.x + threadIdx.x;
  if (n >= NNODE) return;
  float sacc = linb[0];
  #pragma unroll
  for (int c = 0; c < 8; ++c)
    sacc = fmaf(frelu(gat[n*8+c] + bias1[c]), linW[c], sacc);
  x1[n] = sacc;
}

// conv2 is rank-1: per-endpoint features recomputed from scalar x1.
__global__ void edgeA2(const int* __restrict__ ei, const float* __restrict__ x1,
                       const float* __restrict__ Wl2, const float* __restrict__ bl2,
                       const float* __restrict__ Wr2, const float* __restrict__ br2,
                       const float* __restrict__ att,
                       float* __restrict__ elog, float* __restrict__ denom){
  int e = blockIdx.x*blockDim.x + threadIdx.x;
  if (e >= NEDGE + NNODE) return;
  int sN, dN;
  if (e < NEDGE) { sN = ei[e]; dN = ei[NEDGE + e]; } else { sN = dN = e - NEDGE; }
  float xs = x1[sN], xd = x1[dN];
  float l0 = 0.f, l1 = 0.f;
  #pragma unroll
  for (int c = 0; c < 4; ++c) {
    l0 = fmaf(att[c],   lrelu(fmaf(xs, Wl2[c],   bl2[c])   + fmaf(xd, Wr2[c],   br2[c])),   l0);
    l1 = fmaf(att[4+c], lrelu(fmaf(xs, Wl2[4+c], bl2[4+c]) + fmaf(xd, Wr2[4+c], br2[4+c])), l1);
  }
  float e0 = expf(l0), e1 = expf(l1);
  elog[e*2]   = e0;
  elog[e*2+1] = e1;
  atomicAdd(denom + dN*2,     e0);
  atomicAdd(denom + dN*2 + 1, e1);
}

__global__ void edgeB2(const int* __restrict__ ei, const float* __restrict__ elog,
                       const float* __restrict__ denom, const float* __restrict__ x1,
                       const float* __restrict__ Wl2, const float* __restrict__ bl2,
                       float* __restrict__ gat){
  int e = blockIdx.x*blockDim.x + threadIdx.x;
  if (e >= NEDGE + NNODE) return;
  int sN, dN;
  if (e < NEDGE) { sN = ei[e]; dN = ei[NEDGE + e]; } else { sN = dN = e - NEDGE; }
  float al0 = elog[e*2]   / denom[dN*2];
  float al1 = elog[e*2+1] / denom[dN*2 + 1];
  float xs = x1[sN];
  #pragma unroll
  for (int c = 0; c < 4; ++c) {
    atomicAdd(gat + dN*8 + c,     fmaf(xs, Wl2[c],   bl2[c])  *al0);
    atomicAdd(gat + dN*8 + 4 + c, fmaf(xs, Wl2[4+c], bl2[4+c])*al1);
  }
}

// ---------------------------------------------------------------------------
// x2 inline; h1 = relu(encp + x1*W1[9998] + x2*W1[9999] + b1);
// h2 = relu(h1@W2+b2); out = h2@W3 + b3.  One node per wave.
__global__ void enc_finish(const float* __restrict__ encp, const float* __restrict__ x1,
                           const float* __restrict__ gat2, const float* __restrict__ bias2,
                           const float* __restrict__ l2W, const float* __restrict__ l2b,
                           const float* __restrict__ W1, const float* __restrict__ b1,
                           const float* __restrict__ W2, const float* __restrict__ b2,
                           const float* __restrict__ W3, const float* __restrict__ b3,
                           float* __restrict__ out){
  __shared__ float hb[4][64];
  int wv = threadIdx.x >> 6, lane = threadIdx.x & 63;
  int n = blockIdx.x*4 + wv;
  float x2v = l2b[0];
  #pragma unroll
  for (int c = 0; c < 8; ++c)
    x2v = fmaf(frelu(gat2[n*8+c] + bias2[c]), l2W[c], x2v);
  float hv = encp[n*64 + lane] + x1[n]*W1[9998*64 + lane]
           + x2v*W1[9999*64 + lane] + b1[lane];
  hb[wv][lane] = frelu(hv);
  __syncthreads();
  float t = 0.f;
  if (lane < 32) {
    float a2 = b2[lane];
    #pragma unroll
    for (int k = 0; k < 64; ++k) a2 = fmaf(hb[wv][k], W2[k*32 + lane], a2);
    t = frelu(a2) * W3[lane];
  }
  #pragma unroll
  for (int m = 1; m < 64; m <<= 1) t += __shfl_xor(t, m, 64);
  if (lane == 0) out[n] = t + b3[0];
}

// ---------------------------------------------------------------------------
extern "C" void kernel_launch(void* const* d_in, const int* in_sizes, int n_in,
                              void* d_out, int out_size, void* d_ws, size_t ws_size,
                              hipStream_t stream){
  (void)in_sizes; (void)n_in; (void)out_size; (void)ws_size;
  const float* x    = (const float*)d_in[0];
  const int*   ei   = (const int*)  d_in[1];
  const float* Wl1  = (const float*)d_in[2];
  const float* bl1  = (const float*)d_in[3];
  const float* Wr1  = (const float*)d_in[4];
  const float* br1  = (const float*)d_in[5];
  const float* att1 = (const float*)d_in[6];
  const float* bias1= (const float*)d_in[7];
  const float* l1W  = (const float*)d_in[8];
  const float* l1b  = (const float*)d_in[9];
  const float* Wl2  = (const float*)d_in[10];
  const float* bl2  = (const float*)d_in[11];
  const float* Wr2  = (const float*)d_in[12];
  const float* br2  = (const float*)d_in[13];
  const float* att2 = (const float*)d_in[14];
  const float* bias2= (const float*)d_in[15];
  const float* l2W  = (const float*)d_in[16];
  const float* l2b  = (const float*)d_in[17];
  const float* eW1  = (const float*)d_in[18];
  const float* eb1  = (const float*)d_in[19];
  const float* eW2  = (const float*)d_in[20];
  const float* eb2  = (const float*)d_in[21];
  const float* eW3  = (const float*)d_in[22];
  const float* eb3  = (const float*)d_in[23];

  float* ws = (float*)d_ws;
  size_t off = 0;
  auto alloc = [&](size_t nel){ float* pp = ws + off; off += (nel + 63) & ~size_t(63); return pp; };
  _Float16* WhT = (_Float16*)alloc((size_t)80*KPADW/2);
  _Float16* WlT = (_Float16*)alloc((size_t)80*KPADW/2);
  float* elog   = alloc((size_t)(NEDGE+NNODE)*2);
  // contiguous zero block [xl1 .. gat2]:
  float* xl1    = alloc(NNODE*8);
  float* xr1    = alloc(NNODE*8);
  float* encp   = alloc(NNODE*64);
  float* denom1 = alloc(NNODE*2);
  float* gat1   = alloc(NNODE*8);
  float* denom2 = alloc(NNODE*2);
  float* gat2   = alloc(NNODE*8);
  size_t zspan  = (size_t)((gat2 + ((NNODE*8 + 63) & ~63)) - xl1) * sizeof(float);
  float* x1a    = alloc(NNODE);

  const int ET = NEDGE + NNODE;
  const int eb = (ET + 255)/256;

  prep_wt<<<(80*KPADW)/256, 256, 0, stream>>>(Wl1, Wr1, eW1, WhT, WlT);
  hipMemsetAsync(xl1, 0, zspan, stream);

  k1_fused<<<157*KSPLIT, 256, 0, stream>>>(x, WhT, WlT, bl1, br1, xl1, xr1, encp);

  edgeA1<<<eb, 256, 0, stream>>>(ei, xl1, xr1, att1, elog, denom1);
  edgeB1<<<eb, 256, 0, stream>>>(ei, elog, denom1, xl1, gat1);
  node_x1<<<(NNODE+255)/256, 256, 0, stream>>>(gat1, bias1, l1W, l1b, x1a);

  edgeA2<<<eb, 256, 0, stream>>>(ei, x1a, Wl2, bl2, Wr2, br2, att2, elog, denom2);
  edgeB2<<<eb, 256, 0, stream>>>(ei, elog, denom2, x1a, Wl2, bl2, gat2);

  enc_finish<<<NNODE/4, 256, 0, stream>>>(encp, x1a, gat2, bias2, l2W, l2b,
                                          eW1, eb1, eW2, eb2, eW3, eb3,
                                          (float*)d_out);
}

// Round 6
// 694.700 us; speedup vs baseline: 1.6001x; 1.0358x over previous
//
#include <hip/hip_runtime.h>
#include <math.h>

#define NNODE 10000
#define INCH  9998
#define NEDGE 320000
#define KPADW 10240        // padded K for weight arrays
#define KSPLIT 4
#define KRANGE 2560        // K per block
#define NCH   40           // chunks per block (64 k each)
#define ZN    1000064      // floats in the contiguous zero block [xl1..gat2]

typedef _Float16 half8 __attribute__((ext_vector_type(8)));
typedef float    f32x4 __attribute__((ext_vector_type(4)));

__device__ __forceinline__ float lrelu(float v){ return v > 0.f ? v : 0.2f*v; }
__device__ __forceinline__ float frelu(float v){ return v > 0.f ? v : 0.f; }

// ---------------------------------------------------------------------------
// Weight prep (fp16 hi + 2048-scaled residual, col-major-K) + zero-init of the
// accumulation block (folded in to save a launch).
__global__ void prep_wt(const float* __restrict__ Wl, const float* __restrict__ Wr,
                        const float* __restrict__ We, _Float16* __restrict__ WhT,
                        _Float16* __restrict__ WlT, float* __restrict__ zblk){
  int idx = blockIdx.x*256 + threadIdx.x;
  if (idx < ZN) zblk[idx] = 0.f;
  if (idx >= 80*KPADW) return;
  int col = idx / KPADW;
  int k   = idx - col*KPADW;
  float v = 0.f;
  if (k < INCH)
    v = (col < 8) ? Wl[k*8 + col] : (col < 16 ? Wr[k*8 + (col-8)] : We[k*64 + (col-16)]);
  _Float16 h = (_Float16)v;
  _Float16 l = (_Float16)((v - (float)h) * 2048.f);
  WhT[idx] = h;
  WlT[idx] = l;
}

// ---------------------------------------------------------------------------
// Fused 80-col GEMM over x via mfma_f32_16x16x32_f16, split-fp16 (hi+lo/2048).
// Grid: 628 = 157 row-blocks (64 rows) x 4 K-splits. Block: 256 thr = 4 waves,
// each wave 16 rows x 80 cols (5 col-tiles). (256,2): VGPR cap 256 -> no spill
// (round-4's (256,3) cap of ~170 split 64V and spilled 412MB to scratch).
// W chunk reg-staged to LDS; W and x double-buffered in regs across chunks.
__global__ __launch_bounds__(256, 2)
void k1_fused(const float* __restrict__ x, const _Float16* __restrict__ WhT,
              const _Float16* __restrict__ WlT, const float* __restrict__ bl1,
              const float* __restrict__ br1, float* __restrict__ xl1,
              float* __restrict__ xr1, float* __restrict__ encp){
  __shared__ _Float16 lds[2][80][68];   // [hi/lo][col][64k + 4 pad]
  const int tid  = threadIdx.x;
  const int lane = tid & 63;
  const int wv   = tid >> 6;            // 0..3
  const int g    = lane >> 4;           // k-group 0..3
  const int c0   = lane & 15;
  const int kh   = blockIdx.x & (KSPLIT-1);
  const int rb   = blockIdx.x >> 2;     // 0..156
  const int k0b  = kh*KRANGE;
  const int maxi = NNODE*INCH - 2;

  const int arow  = rb*64 + wv*16 + c0;
  const int xbase = (arow < NNODE ? arow : NNODE-1)*INCH;

  f32x4 acc_hi[5], acc_lo[5];
  #pragma unroll
  for (int t = 0; t < 5; ++t){ acc_hi[t] = (f32x4)0.f; acc_lo[t] = (f32x4)0.f; }

  int scol[5], sks[5], ssp[5];
  #pragma unroll
  for (int i = 0; i < 5; ++i){
    int sg = tid + 256*i;               // 16B segments
    int sp = sg >= 640 ? 1 : 0;
    int s2 = sg - sp*640;
    ssp[i] = sp; scol[i] = s2 >> 3; sks[i] = s2 & 7;
  }

  // prefetch chunk 0: W regs + x regs
  uint4 wreg[5];
  #pragma unroll
  for (int i = 0; i < 5; ++i)
    wreg[i] = *(const uint4*)((ssp[i] ? WlT : WhT) + scol[i]*KPADW + k0b + sks[i]*8);
  float2 xn[8];
  #pragma unroll
  for (int s = 0; s < 2; ++s)
    #pragma unroll
    for (int t = 0; t < 4; ++t)
      xn[s*4+t] = *(const float2*)(x + min(xbase + k0b + s*32 + 8*g + 2*t, maxi));

  for (int c = 0; c < NCH; ++c){
    __syncthreads();                    // wreg/xn for chunk c ready; readers done
    #pragma unroll
    for (int i = 0; i < 5; ++i)
      *(uint4*)&lds[ssp[i]][scol[i]][sks[i]*8] = wreg[i];
    __syncthreads();                    // lds visible

    float2 xv[8];
    #pragma unroll
    for (int j = 0; j < 8; ++j) xv[j] = xn[j];

    if (c + 1 < NCH){                   // issue next chunk's loads (overlap MFMA)
      const int k0n = k0b + (c+1)*64;
      #pragma unroll
      for (int i = 0; i < 5; ++i)
        wreg[i] = *(const uint4*)((ssp[i] ? WlT : WhT) + scol[i]*KPADW + k0n + sks[i]*8);
      #pragma unroll
      for (int s = 0; s < 2; ++s)
        #pragma unroll
        for (int t = 0; t < 4; ++t)
          xn[s*4+t] = *(const float2*)(x + min(xbase + k0n + s*32 + 8*g + 2*t, maxi));
    }

    #pragma unroll
    for (int s = 0; s < 2; ++s){        // two K-steps of 32
      float xf[8] = {xv[s*4].x, xv[s*4].y, xv[s*4+1].x, xv[s*4+1].y,
                     xv[s*4+2].x, xv[s*4+2].y, xv[s*4+3].x, xv[s*4+3].y};
      half8 ah, al;
      #pragma unroll
      for (int j = 0; j < 8; ++j){
        _Float16 h = (_Float16)xf[j];
        ah[j] = h;
        al[j] = (_Float16)((xf[j] - (float)h) * 2048.f);
      }
      #pragma unroll
      for (int t = 0; t < 5; ++t){
        half8 bh = *(const half8*)&lds[0][c0 + 16*t][s*32 + g*8];
        half8 bl = *(const half8*)&lds[1][c0 + 16*t][s*32 + g*8];
        acc_hi[t] = __builtin_amdgcn_mfma_f32_16x16x32_f16(ah, bh, acc_hi[t], 0, 0, 0);
        acc_lo[t] = __builtin_amdgcn_mfma_f32_16x16x32_f16(ah, bl, acc_lo[t], 0, 0, 0);
        acc_lo[t] = __builtin_amdgcn_mfma_f32_16x16x32_f16(al, bh, acc_lo[t], 0, 0, 0);
      }
    }
  }

  // epilogue: C/D layout col=lane&15, row=4*(lane>>4)+reg  [m89-verified]
  const float inv2048 = 4.8828125e-4f;
  const int nodeb = rb*64 + wv*16 + 4*g;
  #pragma unroll
  for (int t = 0; t < 5; ++t){
    #pragma unroll
    for (int r = 0; r < 4; ++r){
      int node = nodeb + r;
      if (node < NNODE){
        int col = 16*t + c0;
        float val = acc_hi[t][r] + acc_lo[t][r]*inv2048;
        if (kh == 0){
          if (col < 8)       val += bl1[col];
          else if (col < 16) val += br1[col - 8];
        }
        if (col < 8)       atomicAdd(xl1 + node*8 + col, val);
        else if (col < 16) atomicAdd(xr1 + node*8 + col - 8, val);
        else               atomicAdd(encp + node*64 + col - 16, val);
      }
    }
  }
}

// ---------------------------------------------------------------------------
// conv1 edge pass A: logits -> exp -> store + denom. (No max subtraction:
// logits are O(1); exp safe in fp32; softmax is shift-invariant.)
__global__ void edgeA1(const int* __restrict__ ei, const float* __restrict__ xl,
                       const float* __restrict__ xr, const float* __restrict__ att,
                       float* __restrict__ elog, float* __restrict__ denom){
  int e = blockIdx.x*blockDim.x + threadIdx.x;
  if (e >= NEDGE + NNODE) return;
  int sN, dN;
  if (e < NEDGE) { sN = ei[e]; dN = ei[NEDGE + e]; } else { sN = dN = e - NEDGE; }
  const float4 a0 = *(const float4*)(xl + sN*8);
  const float4 a1 = *(const float4*)(xl + sN*8 + 4);
  const float4 b0 = *(const float4*)(xr + dN*8);
  const float4 b1 = *(const float4*)(xr + dN*8 + 4);
  float l0 = att[0]*lrelu(a0.x+b0.x) + att[1]*lrelu(a0.y+b0.y)
           + att[2]*lrelu(a0.z+b0.z) + att[3]*lrelu(a0.w+b0.w);
  float l1 = att[4]*lrelu(a1.x+b1.x) + att[5]*lrelu(a1.y+b1.y)
           + att[6]*lrelu(a1.z+b1.z) + att[7]*lrelu(a1.w+b1.w);
  float e0 = expf(l0), e1 = expf(l1);
  elog[e*2]   = e0;
  elog[e*2+1] = e1;
  atomicAdd(denom + dN*2,     e0);
  atomicAdd(denom + dN*2 + 1, e1);
}

__global__ void edgeB1(const int* __restrict__ ei, const float* __restrict__ elog,
                       const float* __restrict__ denom, const float* __restrict__ xl,
                       float* __restrict__ gat){
  int e = blockIdx.x*blockDim.x + threadIdx.x;
  if (e >= NEDGE + NNODE) return;
  int sN, dN;
  if (e < NEDGE) { sN = ei[e]; dN = ei[NEDGE + e]; } else { sN = dN = e - NEDGE; }
  float al0 = elog[e*2]   / denom[dN*2];
  float al1 = elog[e*2+1] / denom[dN*2 + 1];
  const float4 a0 = *(const float4*)(xl + sN*8);
  const float4 a1 = *(const float4*)(xl + sN*8 + 4);
  atomicAdd(gat + dN*8 + 0, a0.x*al0);
  atomicAdd(gat + dN*8 + 1, a0.y*al0);
  atomicAdd(gat + dN*8 + 2, a0.z*al0);
  atomicAdd(gat + dN*8 + 3, a0.w*al0);
  atomicAdd(gat + dN*8 + 4, a1.x*al1);
  atomicAdd(gat + dN*8 + 5, a1.y*al1);
  atomicAdd(gat + dN*8 + 6, a1.z*al1);
  atomicAdd(gat + dN*8 + 7, a1.w*al1);
}

// x1 = relu(gat1+bias1)@lin1_W + lin1_b
__global__ void node_x1(const float* __restrict__ gat, const float* __restrict__ bias1,
                        const float* __restrict__ linW, const float* __restrict__ linb,
                        float* __restrict__ x1){
  int n = blockIdx.x*blockDim.x + threadIdx.x;
  if (n >= NNODE) return;
  float sacc = linb[0];
  #pragma unroll
  for (int c = 0; c < 8; ++c)
    sacc = fmaf(frelu(gat[n*8+c] + bias1[c]), linW[c], sacc);
  x1[n] = sacc;
}

// conv2 is rank-1: per-endpoint features recomputed from scalar x1.
__global__ void edgeA2(const int* __restrict__ ei, const float* __restrict__ x1,
                       const float* __restrict__ Wl2, const float* __restrict__ bl2,
                       const float* __restrict__ Wr2, const float* __restrict__ br2,
                       const float* __restrict__ att,
                       float* __restrict__ elog, float* __restrict__ denom){
  int e = blockIdx.x*blockDim.x + threadIdx.x;
  if (e >= NEDGE + NNODE) return;
  int sN, dN;
  if (e < NEDGE) { sN = ei[e]; dN = ei[NEDGE + e]; } else { sN = dN = e - NEDGE; }
  float xs = x1[sN], xd = x1[dN];
  float l0 = 0.f, l1 = 0.f;
  #pragma unroll
  for (int c = 0; c < 4; ++c) {
    l0 = fmaf(att[c],   lrelu(fmaf(xs, Wl2[c],   bl2[c])   + fmaf(xd, Wr2[c],   br2[c])),   l0);
    l1 = fmaf(att[4+c], lrelu(fmaf(xs, Wl2[4+c], bl2[4+c]) + fmaf(xd, Wr2[4+c], br2[4+c])), l1);
  }
  float e0 = expf(l0), e1 = expf(l1);
  elog[e*2]   = e0;
  elog[e*2+1] = e1;
  atomicAdd(denom + dN*2,     e0);
  atomicAdd(denom + dN*2 + 1, e1);
}

__global__ void edgeB2(const int* __restrict__ ei, const float* __restrict__ elog,
                       const float* __restrict__ denom, const float* __restrict__ x1,
                       const float* __restrict__ Wl2, const float* __restrict__ bl2,
                       float* __restrict__ gat){
  int e = blockIdx.x*blockDim.x + threadIdx.x;
  if (e >= NEDGE + NNODE) return;
  int sN, dN;
  if (e < NEDGE) { sN = ei[e]; dN = ei[NEDGE + e]; } else { sN = dN = e - NEDGE; }
  float al0 = elog[e*2]   / denom[dN*2];
  float al1 = elog[e*2+1] / denom[dN*2 + 1];
  float xs = x1[sN];
  #pragma unroll
  for (int c = 0; c < 4; ++c) {
    atomicAdd(gat + dN*8 + c,     fmaf(xs, Wl2[c],   bl2[c])  *al0);
    atomicAdd(gat + dN*8 + 4 + c, fmaf(xs, Wl2[4+c], bl2[4+c])*al1);
  }
}

// ---------------------------------------------------------------------------
// x2 inline; h1 = relu(encp + x1*W1[9998] + x2*W1[9999] + b1);
// h2 = relu(h1@W2+b2); out = h2@W3 + b3.  One node per wave.
__global__ void enc_finish(const float* __restrict__ encp, const float* __restrict__ x1,
                           const float* __restrict__ gat2, const float* __restrict__ bias2,
                           const float* __restrict__ l2W, const float* __restrict__ l2b,
                           const float* __restrict__ W1, const float* __restrict__ b1,
                           const float* __restrict__ W2, const float* __restrict__ b2,
                           const float* __restrict__ W3, const float* __restrict__ b3,
                           float* __restrict__ out){
  __shared__ float hb[4][64];
  int wv = threadIdx.x >> 6, lane = threadIdx.x & 63;
  int n = blockIdx.x*4 + wv;
  float x2v = l2b[0];
  #pragma unroll
  for (int c = 0; c < 8; ++c)
    x2v = fmaf(frelu(gat2[n*8+c] + bias2[c]), l2W[c], x2v);
  float hv = encp[n*64 + lane] + x1[n]*W1[9998*64 + lane]
           + x2v*W1[9999*64 + lane] + b1[lane];
  hb[wv][lane] = frelu(hv);
  __syncthreads();
  float t = 0.f;
  if (lane < 32) {
    float a2 = b2[lane];
    #pragma unroll
    for (int k = 0; k < 64; ++k) a2 = fmaf(hb[wv][k], W2[k*32 + lane], a2);
    t = frelu(a2) * W3[lane];
  }
  #pragma unroll
  for (int m = 1; m < 64; m <<= 1) t += __shfl_xor(t, m, 64);
  if (lane == 0) out[n] = t + b3[0];
}

// ---------------------------------------------------------------------------
extern "C" void kernel_launch(void* const* d_in, const int* in_sizes, int n_in,
                              void* d_out, int out_size, void* d_ws, size_t ws_size,
                              hipStream_t stream){
  (void)in_sizes; (void)n_in; (void)out_size; (void)ws_size;
  const float* x    = (const float*)d_in[0];
  const int*   ei   = (const int*)  d_in[1];
  const float* Wl1  = (const float*)d_in[2];
  const float* bl1  = (const float*)d_in[3];
  const float* Wr1  = (const float*)d_in[4];
  const float* br1  = (const float*)d_in[5];
  const float* att1 = (const float*)d_in[6];
  const float* bias1= (const float*)d_in[7];
  const float* l1W  = (const float*)d_in[8];
  const float* l1b  = (const float*)d_in[9];
  const float* Wl2  = (const float*)d_in[10];
  const float* bl2  = (const float*)d_in[11];
  const float* Wr2  = (const float*)d_in[12];
  const float* br2  = (const float*)d_in[13];
  const float* att2 = (const float*)d_in[14];
  const float* bias2= (const float*)d_in[15];
  const float* l2W  = (const float*)d_in[16];
  const float* l2b  = (const float*)d_in[17];
  const float* eW1  = (const float*)d_in[18];
  const float* eb1  = (const float*)d_in[19];
  const float* eW2  = (const float*)d_in[20];
  const float* eb2  = (const float*)d_in[21];
  const float* eW3  = (const float*)d_in[22];
  const float* eb3  = (const float*)d_in[23];

  float* ws = (float*)d_ws;
  size_t off = 0;
  auto alloc = [&](size_t nel){ float* pp = ws + off; off += (nel + 63) & ~size_t(63); return pp; };
  _Float16* WhT = (_Float16*)alloc((size_t)80*KPADW/2);
  _Float16* WlT = (_Float16*)alloc((size_t)80*KPADW/2);
  float* elog   = alloc((size_t)(NEDGE+NNODE)*2);
  // contiguous zero block [xl1 .. gat2] = ZN floats:
  float* xl1    = alloc(NNODE*8);
  float* xr1    = alloc(NNODE*8);
  float* encp   = alloc(NNODE*64);
  float* denom1 = alloc(NNODE*2);
  float* gat1   = alloc(NNODE*8);
  float* denom2 = alloc(NNODE*2);
  float* gat2   = alloc(NNODE*8);
  float* x1a    = alloc(NNODE);

  const int ET = NEDGE + NNODE;
  const int eb = (ET + 255)/256;

  prep_wt<<<(ZN + 255)/256, 256, 0, stream>>>(Wl1, Wr1, eW1, WhT, WlT, xl1);

  k1_fused<<<157*KSPLIT, 256, 0, stream>>>(x, WhT, WlT, bl1, br1, xl1, xr1, encp);

  edgeA1<<<eb, 256, 0, stream>>>(ei, xl1, xr1, att1, elog, denom1);
  edgeB1<<<eb, 256, 0, stream>>>(ei, elog, denom1, xl1, gat1);
  node_x1<<<(NNODE+255)/256, 256, 0, stream>>>(gat1, bias1, l1W, l1b, x1a);

  edgeA2<<<eb, 256, 0, stream>>>(ei, x1a, Wl2, bl2, Wr2, br2, att2, elog, denom2);
  edgeB2<<<eb, 256, 0, stream>>>(ei, elog, denom2, x1a, Wl2, bl2, gat2);

  enc_finish<<<NNODE/4, 256, 0, stream>>>(encp, x1a, gat2, bias2, l2W, l2b,
                                          eW1, eb1, eW2, eb2, eW3, eb3,
                                          (float*)d_out);
}

// Round 7
// 682.285 us; speedup vs baseline: 1.6292x; 1.0182x over previous
//
#include <hip/hip_runtime.h>
#include <math.h>

#define NNODE 10000
#define INCH  9998
#define NEDGE 320000
#define KPADW 10240        // padded K (160 chunks of 64)
#define KSPLIT 4
#define KRANGE 2560        // K per block
#define NCH   40           // chunks per block (64 k each)
#define CHW   10880        // halves per W chunk image: 2*80*68
#define ZN    1000064      // floats in the contiguous zero block [xl1..gat2]

typedef _Float16 half8 __attribute__((ext_vector_type(8)));
typedef float    f32x4 __attribute__((ext_vector_type(4)));

__device__ __forceinline__ float lrelu(float v){ return v > 0.f ? v : 0.2f*v; }
__device__ __forceinline__ float frelu(float v){ return v > 0.f ? v : 0.f; }

#define GLOAD_LDS16(g, l) __builtin_amdgcn_global_load_lds( \
    (const __attribute__((address_space(1))) unsigned int*)(g), \
    (__attribute__((address_space(3))) unsigned int*)(l), 16, 0, 0)

// ---------------------------------------------------------------------------
// Weight prep: Wimg[chunk][sp][col][k68] — per-64k-chunk LDS images in the
// exact padded [2][80][68] layout, so k1 stages with linear global_load_lds
// (T21: swizzle/pad on BOTH sides). sp0=fp16 hi, sp1=2048-scaled residual.
// Also zero-inits the accumulation block (saves a launch).
__global__ void prep_wt(const float* __restrict__ Wl, const float* __restrict__ Wr,
                        const float* __restrict__ We, _Float16* __restrict__ Wimg,
                        float* __restrict__ zblk){
  int idx = blockIdx.x*256 + threadIdx.x;
  if (idx < ZN) zblk[idx] = 0.f;
  if (idx >= 160*CHW) return;
  int ci   = idx / CHW;
  int rem  = idx - ci*CHW;
  int sp   = rem / 5440;
  int rem2 = rem - sp*5440;
  int col  = rem2 / 68;
  int k68  = rem2 - col*68;
  int k    = ci*64 + k68;
  float v = 0.f;
  if (k68 < 64 && k < INCH)
    v = (col < 8) ? Wl[k*8 + col] : (col < 16 ? Wr[k*8 + (col-8)] : We[k*64 + (col-16)]);
  _Float16 h = (_Float16)v;
  Wimg[idx] = sp ? (_Float16)((v - (float)h) * 2048.f) : h;
}

// ---------------------------------------------------------------------------
// Fused 80-col GEMM over x via mfma_f32_16x16x32_f16, split-fp16 (hi+lo/2048).
// Grid: 628 = 157 row-blocks (64 rows) x 4 K-splits. Block: 256 thr = 4 waves,
// each wave 16 rows x 80 cols (5 col-tiles). ALL per-thread arrays eliminated
// (named scalars + global_load_lds) — rule #20: arrays went to scratch in r4/r6
// (WRITE_SIZE 405MB = xn[8] 64B x 40 chunks x 160K threads).
#define TILE(T, AH, AL, LB, KOFF, H, L) { \
  half8 bh = *(const half8*)((LB) + (16*(T)+c0)*68 + (KOFF)); \
  half8 bl = *(const half8*)((LB) + 5440 + (16*(T)+c0)*68 + (KOFF)); \
  H = __builtin_amdgcn_mfma_f32_16x16x32_f16(AH, bh, H, 0, 0, 0); \
  L = __builtin_amdgcn_mfma_f32_16x16x32_f16(AH, bl, L, 0, 0, 0); \
  L = __builtin_amdgcn_mfma_f32_16x16x32_f16(AL, bh, L, 0, 0, 0); }

#define KSTEP(XA, XB, XC, XD, LB, KOFF) { \
  _Float16 h0_=(_Float16)XA.x, h1_=(_Float16)XA.y, h2_=(_Float16)XB.x, h3_=(_Float16)XB.y; \
  _Float16 h4_=(_Float16)XC.x, h5_=(_Float16)XC.y, h6_=(_Float16)XD.x, h7_=(_Float16)XD.y; \
  half8 ah = {h0_,h1_,h2_,h3_,h4_,h5_,h6_,h7_}; \
  half8 al = {(_Float16)((XA.x-(float)h0_)*2048.f), (_Float16)((XA.y-(float)h1_)*2048.f), \
              (_Float16)((XB.x-(float)h2_)*2048.f), (_Float16)((XB.y-(float)h3_)*2048.f), \
              (_Float16)((XC.x-(float)h4_)*2048.f), (_Float16)((XC.y-(float)h5_)*2048.f), \
              (_Float16)((XD.x-(float)h6_)*2048.f), (_Float16)((XD.y-(float)h7_)*2048.f)}; \
  TILE(0, ah, al, LB, KOFF, ach0, acl0) \
  TILE(1, ah, al, LB, KOFF, ach1, acl1) \
  TILE(2, ah, al, LB, KOFF, ach2, acl2) \
  TILE(3, ah, al, LB, KOFF, ach3, acl3) \
  TILE(4, ah, al, LB, KOFF, ach4, acl4) }

#define STAGE(CI, DB) { \
  const _Float16* wsrc = Wimg + (size_t)(CI)*CHW; \
  _Float16* dst = ldsb + (DB)*CHW; \
  GLOAD_LDS16(wsrc + (size_t)(tid       )*8, dst + (size_t)(tid       )*8); \
  GLOAD_LDS16(wsrc + (size_t)(tid +  256)*8, dst + (size_t)(tid +  256)*8); \
  GLOAD_LDS16(wsrc + (size_t)(tid +  512)*8, dst + (size_t)(tid +  512)*8); \
  GLOAD_LDS16(wsrc + (size_t)(tid +  768)*8, dst + (size_t)(tid +  768)*8); \
  GLOAD_LDS16(wsrc + (size_t)(tid + 1024)*8, dst + (size_t)(tid + 1024)*8); \
  if (tid < 80) GLOAD_LDS16(wsrc + (size_t)(tid + 1280)*8, dst + (size_t)(tid + 1280)*8); }

#define XLOAD(X0, X1, X2, X3, X4, X5, X6, X7, KB) { \
  X0 = *(const float2*)(x + min(xbase + (KB)     , maxi)); \
  X1 = *(const float2*)(x + min(xbase + (KB) +  2, maxi)); \
  X2 = *(const float2*)(x + min(xbase + (KB) +  4, maxi)); \
  X3 = *(const float2*)(x + min(xbase + (KB) +  6, maxi)); \
  X4 = *(const float2*)(x + min(xbase + (KB) + 32, maxi)); \
  X5 = *(const float2*)(x + min(xbase + (KB) + 34, maxi)); \
  X6 = *(const float2*)(x + min(xbase + (KB) + 36, maxi)); \
  X7 = *(const float2*)(x + min(xbase + (KB) + 38, maxi)); }

#define EPI(T, H, L) { \
  int col = 16*(T) + c0; \
  float v0 = H[0] + L[0]*inv2048; \
  float v1 = H[1] + L[1]*inv2048; \
  float v2 = H[2] + L[2]*inv2048; \
  float v3 = H[3] + L[3]*inv2048; \
  if (kh == 0){ \
    float bb = (col < 8) ? bl1[col] : (col < 16 ? br1[col-8] : 0.f); \
    v0 += bb; v1 += bb; v2 += bb; v3 += bb; \
  } \
  float* dst; int st; \
  if (col < 8)       { dst = xl1 + nodeb*8 + col;        st = 8; } \
  else if (col < 16) { dst = xr1 + nodeb*8 + col - 8;    st = 8; } \
  else               { dst = encp + nodeb*64 + col - 16; st = 64; } \
  atomicAdd(dst,        v0); \
  atomicAdd(dst + st,   v1); \
  atomicAdd(dst + 2*st, v2); \
  atomicAdd(dst + 3*st, v3); }

__global__ __launch_bounds__(256, 2)
void k1_fused(const float* __restrict__ x, const _Float16* __restrict__ Wimg,
              const float* __restrict__ bl1, const float* __restrict__ br1,
              float* __restrict__ xl1, float* __restrict__ xr1,
              float* __restrict__ encp){
  __shared__ _Float16 ldsbuf[2*CHW];
  _Float16* ldsb = ldsbuf;
  const int tid  = threadIdx.x;
  const int lane = tid & 63;
  const int wv   = tid >> 6;            // 0..3
  const int g    = lane >> 4;           // k-group 0..3
  const int c0   = lane & 15;
  const int kh   = blockIdx.x & (KSPLIT-1);
  const int rb   = blockIdx.x >> 2;     // 0..156
  const int ci0  = kh*NCH;              // first global chunk id
  const int k0b  = kh*KRANGE;
  const int maxi = NNODE*INCH - 2;

  const int arow  = rb*64 + wv*16 + c0;
  const int xbase = (arow < NNODE ? arow : NNODE-1)*INCH;

  f32x4 ach0={0,0,0,0}, ach1={0,0,0,0}, ach2={0,0,0,0}, ach3={0,0,0,0}, ach4={0,0,0,0};
  f32x4 acl0={0,0,0,0}, acl1={0,0,0,0}, acl2={0,0,0,0}, acl3={0,0,0,0}, acl4={0,0,0,0};

  // prologue: stage chunk 0 into buf 0; prefetch x chunk 0 into named regs
  STAGE(ci0, 0);
  float2 xn0,xn1,xn2,xn3,xn4,xn5,xn6,xn7;
  XLOAD(xn0,xn1,xn2,xn3,xn4,xn5,xn6,xn7, k0b + 8*g);

  for (int c = 0; c < NCH; ++c){
    const int cur = c & 1;
    __syncthreads();                    // drains vmcnt(0): stage(c) + xn landed

    if (c + 1 < NCH) STAGE(ci0 + c + 1, cur^1);   // async into other buffer

    float2 xv0=xn0, xv1=xn1, xv2=xn2, xv3=xn3, xv4=xn4, xv5=xn5, xv6=xn6, xv7=xn7;
    if (c + 1 < NCH)
      XLOAD(xn0,xn1,xn2,xn3,xn4,xn5,xn6,xn7, k0b + (c+1)*64 + 8*g);

    const _Float16* lb = ldsb + cur*CHW;
    KSTEP(xv0, xv1, xv2, xv3, lb, g*8);          // K-step s=0
    KSTEP(xv4, xv5, xv6, xv7, lb, 32 + g*8);     // K-step s=1
  }

  // epilogue: C/D layout col=lane&15, row=4*(lane>>4)+reg  [m89-verified]
  const float inv2048 = 4.8828125e-4f;
  const int nodeb = rb*64 + wv*16 + 4*g;         // rows nodeb..nodeb+3 (always <NNODE: 157*64=10048, last rb rows 9984..10047 — guard below)
  if (nodeb + 3 < NNODE){
    EPI(0, ach0, acl0) EPI(1, ach1, acl1) EPI(2, ach2, acl2)
    EPI(3, ach3, acl3) EPI(4, ach4, acl4)
  } else {
    // tail rows: per-row guard (rare path, last row-block only)
    #define EPIG(T, H, L) { \
      int col = 16*(T) + c0; \
      float b0 = (kh==0) ? ((col<8)?bl1[col]:(col<16?br1[col-8]:0.f)) : 0.f; \
      float vv0 = H[0] + L[0]*inv2048 + b0; \
      float vv1 = H[1] + L[1]*inv2048 + b0; \
      float vv2 = H[2] + L[2]*inv2048 + b0; \
      float vv3 = H[3] + L[3]*inv2048 + b0; \
      int base; float* dst; int st; \
      if (col < 8)       { dst = xl1;  base = col;      st = 8; } \
      else if (col < 16) { dst = xr1;  base = col - 8;  st = 8; } \
      else               { dst = encp; base = col - 16; st = 64; } \
      if (nodeb     < NNODE) atomicAdd(dst + (nodeb  )*st + base, vv0); \
      if (nodeb + 1 < NNODE) atomicAdd(dst + (nodeb+1)*st + base, vv1); \
      if (nodeb + 2 < NNODE) atomicAdd(dst + (nodeb+2)*st + base, vv2); \
      if (nodeb + 3 < NNODE) atomicAdd(dst + (nodeb+3)*st + base, vv3); }
    EPIG(0, ach0, acl0) EPIG(1, ach1, acl1) EPIG(2, ach2, acl2)
    EPIG(3, ach3, acl3) EPIG(4, ach4, acl4)
  }
}

// ---------------------------------------------------------------------------
// conv1 edge pass A: logits -> exp -> store + denom. (No max subtraction:
// logits are O(1); exp safe in fp32; softmax is shift-invariant.)
__global__ void edgeA1(const int* __restrict__ ei, const float* __restrict__ xl,
                       const float* __restrict__ xr, const float* __restrict__ att,
                       float* __restrict__ elog, float* __restrict__ denom){
  int e = blockIdx.x*blockDim.x + threadIdx.x;
  if (e >= NEDGE + NNODE) return;
  int sN, dN;
  if (e < NEDGE) { sN = ei[e]; dN = ei[NEDGE + e]; } else { sN = dN = e - NEDGE; }
  const float4 a0 = *(const float4*)(xl + sN*8);
  const float4 a1 = *(const float4*)(xl + sN*8 + 4);
  const float4 b0 = *(const float4*)(xr + dN*8);
  const float4 b1 = *(const float4*)(xr + dN*8 + 4);
  float l0 = att[0]*lrelu(a0.x+b0.x) + att[1]*lrelu(a0.y+b0.y)
           + att[2]*lrelu(a0.z+b0.z) + att[3]*lrelu(a0.w+b0.w);
  float l1 = att[4]*lrelu(a1.x+b1.x) + att[5]*lrelu(a1.y+b1.y)
           + att[6]*lrelu(a1.z+b1.z) + att[7]*lrelu(a1.w+b1.w);
  float e0 = expf(l0), e1 = expf(l1);
  elog[e*2]   = e0;
  elog[e*2+1] = e1;
  atomicAdd(denom + dN*2,     e0);
  atomicAdd(denom + dN*2 + 1, e1);
}

__global__ void edgeB1(const int* __restrict__ ei, const float* __restrict__ elog,
                       const float* __restrict__ denom, const float* __restrict__ xl,
                       float* __restrict__ gat){
  int e = blockIdx.x*blockDim.x + threadIdx.x;
  if (e >= NEDGE + NNODE) return;
  int sN, dN;
  if (e < NEDGE) { sN = ei[e]; dN = ei[NEDGE + e]; } else { sN = dN = e - NEDGE; }
  float al0 = elog[e*2]   / denom[dN*2];
  float al1 = elog[e*2+1] / denom[dN*2 + 1];
  const float4 a0 = *(const float4*)(xl + sN*8);
  const float4 a1 = *(const float4*)(xl + sN*8 + 4);
  atomicAdd(gat + dN*8 + 0, a0.x*al0);
  atomicAdd(gat + dN*8 + 1, a0.y*al0);
  atomicAdd(gat + dN*8 + 2, a0.z*al0);
  atomicAdd(gat + dN*8 + 3, a0.w*al0);
  atomicAdd(gat + dN*8 + 4, a1.x*al1);
  atomicAdd(gat + dN*8 + 5, a1.y*al1);
  atomicAdd(gat + dN*8 + 6, a1.z*al1);
  atomicAdd(gat + dN*8 + 7, a1.w*al1);
}

// x1 = relu(gat1+bias1)@lin1_W + lin1_b
__global__ void node_x1(const float* __restrict__ gat, const float* __restrict__ bias1,
                        const float* __restrict__ linW, const float* __restrict__ linb,
                        float* __restrict__ x1){
  int n = blockIdx.x*blockDim.x + threadIdx.x;
  if (n >= NNODE) return;
  float sacc = linb[0];
  #pragma unroll
  for (int c = 0; c < 8; ++c)
    sacc = fmaf(frelu(gat[n*8+c] + bias1[c]), linW[c], sacc);
  x1[n] = sacc;
}

// conv2 is rank-1: per-endpoint features recomputed from scalar x1.
__global__ void edgeA2(const int* __restrict__ ei, const float* __restrict__ x1,
                       const float* __restrict__ Wl2, const float* __restrict__ bl2,
                       const float* __restrict__ Wr2, const float* __restrict__ br2,
                       const float* __restrict__ att,
                       float* __restrict__ elog, float* __restrict__ denom){
  int e = blockIdx.x*blockDim.x + threadIdx.x;
  if (e >= NEDGE + NNODE) return;
  int sN, dN;
  if (e < NEDGE) { sN = ei[e]; dN = ei[NEDGE + e]; } else { sN = dN = e - NEDGE; }
  float xs = x1[sN], xd = x1[dN];
  float l0 = 0.f, l1 = 0.f;
  #pragma unroll
  for (int c = 0; c < 4; ++c) {
    l0 = fmaf(att[c],   lrelu(fmaf(xs, Wl2[c],   bl2[c])   + fmaf(xd, Wr2[c],   br2[c])),   l0);
    l1 = fmaf(att[4+c], lrelu(fmaf(xs, Wl2[4+c], bl2[4+c]) + fmaf(xd, Wr2[4+c], br2[4+c])), l1);
  }
  float e0 = expf(l0), e1 = expf(l1);
  elog[e*2]   = e0;
  elog[e*2+1] = e1;
  atomicAdd(denom + dN*2,     e0);
  atomicAdd(denom + dN*2 + 1, e1);
}

__global__ void edgeB2(const int* __restrict__ ei, const float* __restrict__ elog,
                       const float* __restrict__ denom, const float* __restrict__ x1,
                       const float* __restrict__ Wl2, const float* __restrict__ bl2,
                       float* __restrict__ gat){
  int e = blockIdx.x*blockDim.x + threadIdx.x;
  if (e >= NEDGE + NNODE) return;
  int sN, dN;
  if (e < NEDGE) { sN = ei[e]; dN = ei[NEDGE + e]; } else { sN = dN = e - NEDGE; }
  float al0 = elog[e*2]   / denom[dN*2];
  float al1 = elog[e*2+1] / denom[dN*2 + 1];
  float xs = x1[sN];
  #pragma unroll
  for (int c = 0; c < 4; ++c) {
    atomicAdd(gat + dN*8 + c,     fmaf(xs, Wl2[c],   bl2[c])  *al0);
    atomicAdd(gat + dN*8 + 4 + c, fmaf(xs, Wl2[4+c], bl2[4+c])*al1);
  }
}

// ---------------------------------------------------------------------------
// x2 inline; h1 = relu(encp + x1*W1[9998] + x2*W1[9999] + b1);
// h2 = relu(h1@W2+b2); out = h2@W3 + b3.  One node per wave.
__global__ void enc_finish(const float* __restrict__ encp, const float* __restrict__ x1,
                           const float* __restrict__ gat2, const float* __restrict__ bias2,
                           const float* __restrict__ l2W, const float* __restrict__ l2b,
                           const float* __restrict__ W1, const float* __restrict__ b1,
                           const float* __restrict__ W2, const float* __restrict__ b2,
                           const float* __restrict__ W3, const float* __restrict__ b3,
                           float* __restrict__ out){
  __shared__ float hb[4][64];
  int wv = threadIdx.x >> 6, lane = threadIdx.x & 63;
  int n = blockIdx.x*4 + wv;
  float x2v = l2b[0];
  #pragma unroll
  for (int c = 0; c < 8; ++c)
    x2v = fmaf(frelu(gat2[n*8+c] + bias2[c]), l2W[c], x2v);
  float hv = encp[n*64 + lane] + x1[n]*W1[9998*64 + lane]
           + x2v*W1[9999*64 + lane] + b1[lane];
  hb[wv][lane] = frelu(hv);
  __syncthreads();
  float t = 0.f;
  if (lane < 32) {
    float a2 = b2[lane];
    #pragma unroll
    for (int k = 0; k < 64; ++k) a2 = fmaf(hb[wv][k], W2[k*32 + lane], a2);
    t = frelu(a2) * W3[lane];
  }
  #pragma unroll
  for (int m = 1; m < 64; m <<= 1) t += __shfl_xor(t, m, 64);
  if (lane == 0) out[n] = t + b3[0];
}

// ---------------------------------------------------------------------------
extern "C" void kernel_launch(void* const* d_in, const int* in_sizes, int n_in,
                              void* d_out, int out_size, void* d_ws, size_t ws_size,
                              hipStream_t stream){
  (void)in_sizes; (void)n_in; (void)out_size; (void)ws_size;
  const float* x    = (const float*)d_in[0];
  const int*   ei   = (const int*)  d_in[1];
  const float* Wl1  = (const float*)d_in[2];
  const float* bl1  = (const float*)d_in[3];
  const float* Wr1  = (const float*)d_in[4];
  const float* br1  = (const float*)d_in[5];
  const float* att1 = (const float*)d_in[6];
  const float* bias1= (const float*)d_in[7];
  const float* l1W  = (const float*)d_in[8];
  const float* l1b  = (const float*)d_in[9];
  const float* Wl2  = (const float*)d_in[10];
  const float* bl2  = (const float*)d_in[11];
  const float* Wr2  = (const float*)d_in[12];
  const float* br2  = (const float*)d_in[13];
  const float* att2 = (const float*)d_in[14];
  const float* bias2= (const float*)d_in[15];
  const float* l2W  = (const float*)d_in[16];
  const float* l2b  = (const float*)d_in[17];
  const float* eW1  = (const float*)d_in[18];
  const float* eb1  = (const float*)d_in[19];
  const float* eW2  = (const float*)d_in[20];
  const float* eb2  = (const float*)d_in[21];
  const float* eW3  = (const float*)d_in[22];
  const float* eb3  = (const float*)d_in[23];

  float* ws = (float*)d_ws;
  size_t off = 0;
  auto alloc = [&](size_t nel){ float* pp = ws + off; off += (nel + 63) & ~size_t(63); return pp; };
  _Float16* Wimg = (_Float16*)alloc((size_t)160*CHW/2);   // 3.48 MB of halves
  float* elog   = alloc((size_t)(NEDGE+NNODE)*2);
  // contiguous zero block [xl1 .. gat2] = ZN floats:
  float* xl1    = alloc(NNODE*8);
  float* xr1    = alloc(NNODE*8);
  float* encp   = alloc(NNODE*64);
  float* denom1 = alloc(NNODE*2);
  float* gat1   = alloc(NNODE*8);
  float* denom2 = alloc(NNODE*2);
  float* gat2   = alloc(NNODE*8);
  float* x1a    = alloc(NNODE);

  const int ET = NEDGE + NNODE;
  const int eb = (ET + 255)/256;

  prep_wt<<<(160*CHW + 255)/256, 256, 0, stream>>>(Wl1, Wr1, eW1, Wimg, xl1);

  k1_fused<<<157*KSPLIT, 256, 0, stream>>>(x, Wimg, bl1, br1, xl1, xr1, encp);

  edgeA1<<<eb, 256, 0, stream>>>(ei, xl1, xr1, att1, elog, denom1);
  edgeB1<<<eb, 256, 0, stream>>>(ei, elog, denom1, xl1, gat1);
  node_x1<<<(NNODE+255)/256, 256, 0, stream>>>(gat1, bias1, l1W, l1b, x1a);

  edgeA2<<<eb, 256, 0, stream>>>(ei, x1a, Wl2, bl2, Wr2, br2, att2, elog, denom2);
  edgeB2<<<eb, 256, 0, stream>>>(ei, elog, denom2, x1a, Wl2, bl2, gat2);

  enc_finish<<<NNODE/4, 256, 0, stream>>>(encp, x1a, gat2, bias2, l2W, l2b,
                                          eW1, eb1, eW2, eb2, eW3, eb3,
                                          (float*)d_out);
}